// Round 2
// baseline (309.718 us; speedup 1.0000x reference)
//
#include <hip/hip_runtime.h>

#define B_ 4
#define N_ 4096
#define D_ 64
#define NG (N_ / 32)   // 128 col-groups of 32 per batch

typedef __bf16 bf16_t;
typedef bf16_t bf16x8 __attribute__((ext_vector_type(8)));
typedef float f32x16 __attribute__((ext_vector_type(16)));
typedef float f32x4 __attribute__((ext_vector_type(4)));

// Prologue: fp32 X -> bf16 in MFMA-fragment-swizzled order + row squared-norms.
// Block = (b, g) covering 32 rows. Wave w = k-slice kb (16 k's). Lane l
// (mcol=l&31, half=l>>5) holds X[row=g*32+mcol][k=kb*16+half*8+j], j=0..7,
// stored at Bs[chunk(b,g,kb)*512 + l*8 + j]. Main-kernel fragment loads are
// then lane-contiguous 16 B/lane (one dense 1 KB wave-load per fragment),
// instead of a 32-line strided gather.
__global__ __launch_bounds__(256) void swizzle_norm_kernel(
        const float* __restrict__ X,
        bf16_t* __restrict__ Bs,
        float* __restrict__ norms) {
    const int tid  = threadIdx.x;
    const int kb   = tid >> 6;
    const int lane = tid & 63;
    const int mcol = lane & 31;
    const int half = lane >> 5;
    const int b = blockIdx.x >> 7;
    const int g = blockIdx.x & (NG - 1);

    const int row = g * 32 + mcol;
    const float* src = X + (size_t)(b * N_ + row) * D_ + kb * 16 + half * 8;
    f32x4 x0 = *(const f32x4*)(src);
    f32x4 x1 = *(const f32x4*)(src + 4);

    bf16x8 v;
    float p = 0.f;
    #pragma unroll
    for (int j = 0; j < 4; ++j) { v[j]     = (bf16_t)x0[j]; p += x0[j] * x0[j]; }
    #pragma unroll
    for (int j = 0; j < 4; ++j) { v[4 + j] = (bf16_t)x1[j]; p += x1[j] * x1[j]; }

    bf16_t* dst = Bs + ((size_t)((b * NG + g) * 4 + kb)) * 512 + lane * 8;
    *(bf16x8*)dst = v;

    // row norm: combine the two k-halves within the wave, then the 4 k-slices.
    p += __shfl_xor(p, 32);
    __shared__ float pn[4][32];
    if (half == 0) pn[kb][mcol] = p;
    __syncthreads();
    if (tid < 32)
        norms[b * N_ + g * 32 + tid] =
            pn[0][tid] + pn[1][tid] + pn[2][tid] + pn[3][tid];
}

// One 32x32 S-tile (K=64) = 4 MFMAs; fragments from the swizzled buffer.
__device__ __forceinline__ f32x16 tile_mm(const bf16_t* __restrict__ chunk,
                                          int lane,
                                          bf16x8 a0, bf16x8 a1,
                                          bf16x8 a2, bf16x8 a3) {
    bf16x8 b0 = *(const bf16x8*)(chunk + lane * 8);
    bf16x8 b1 = *(const bf16x8*)(chunk + 512 + lane * 8);
    bf16x8 b2 = *(const bf16x8*)(chunk + 1024 + lane * 8);
    bf16x8 b3 = *(const bf16x8*)(chunk + 1536 + lane * 8);
    f32x16 acc;
    #pragma unroll
    for (int i = 0; i < 16; ++i) acc[i] = 0.0f;
    acc = __builtin_amdgcn_mfma_f32_32x32x16_bf16(a0, b0, acc, 0, 0, 0);
    acc = __builtin_amdgcn_mfma_f32_32x32x16_bf16(a1, b1, acc, 0, 0, 0);
    acc = __builtin_amdgcn_mfma_f32_32x32x16_bf16(a2, b2, acc, 0, 0, 0);
    acc = __builtin_amdgcn_mfma_f32_32x32x16_bf16(a3, b3, acc, 0, 0, 0);
    return acc;
}

// Main: block owns 32 rows of one batch. Pass 1: denominators via
// lse = |x|^2 + log(sum exp(s - |x|^2)). Pass 2: recompute S, write exp(s-lse)
// with nontemporal stores (output is never re-read; keep X resident in L2).
__global__ __launch_bounds__(256) void softmax_xxt_kernel(
        const bf16_t* __restrict__ Bs,
        const float* __restrict__ norms,
        float* __restrict__ Out) {
    const int tid  = threadIdx.x;
    const int wave = tid >> 6;
    const int lane = tid & 63;
    const int b    = blockIdx.x >> 7;
    const int ga   = blockIdx.x & (NG - 1);     // row-group
    const int rowbase = ga * 32;
    const int half = lane >> 5;

    const bf16_t* Bsb = Bs + (size_t)(b * NG) * 2048;  // 4 chunks * 512 per group

    // A fragments: same operand layout as B, from the swizzled buffer.
    const bf16_t* achunk = Bsb + (size_t)ga * 2048;
    const bf16x8 a0 = *(const bf16x8*)(achunk + lane * 8);
    const bf16x8 a1 = *(const bf16x8*)(achunk + 512 + lane * 8);
    const bf16x8 a2 = *(const bf16x8*)(achunk + 1024 + lane * 8);
    const bf16x8 a3 = *(const bf16x8*)(achunk + 1536 + lane * 8);

    // Stabilizer m = |x_row|^2 for the 16 rows this lane's acc regs map to:
    // row = (reg&3) + 8*(reg>>2) + 4*(lane>>5)
    float lse[16];
    {
        const float* nb = norms + b * N_ + rowbase;
        #pragma unroll
        for (int r = 0; r < 16; ++r) {
            int row = (r & 3) + 8 * (r >> 2) + 4 * half;
            lse[r] = nb[row];
        }
    }

    __shared__ float partials[4][32];

    // ---------------- pass 1: denominators ----------------
    float sums[16];
    #pragma unroll
    for (int r = 0; r < 16; ++r) sums[r] = 0.0f;

    for (int t = 0; t < NG / 4; ++t) {
        const int g = t * 4 + wave;                 // wave-private col-group
        f32x16 acc = tile_mm(Bsb + (size_t)g * 2048, lane, a0, a1, a2, a3);
        #pragma unroll
        for (int r = 0; r < 16; ++r) sums[r] += __expf(acc[r] - lse[r]);
    }

    // reduce over the 32 lanes (cols) of each half-wave
    #pragma unroll
    for (int r = 0; r < 16; ++r) {
        float s = sums[r];
        s += __shfl_xor(s, 1);
        s += __shfl_xor(s, 2);
        s += __shfl_xor(s, 4);
        s += __shfl_xor(s, 8);
        s += __shfl_xor(s, 16);
        sums[r] = s;
    }

    // cross-wave combine (each wave covered a different col span)
    const int mcol = lane & 31;
    if (mcol == 0) {
        #pragma unroll
        for (int r = 0; r < 16; ++r) {
            int row = (r & 3) + 8 * (r >> 2) + 4 * half;
            partials[wave][row] = sums[r];
        }
    }
    __syncthreads();

    #pragma unroll
    for (int r = 0; r < 16; ++r) {
        int row = (r & 3) + 8 * (r >> 2) + 4 * half;
        float tot = partials[0][row] + partials[1][row] +
                    partials[2][row] + partials[3][row];
        lse[r] += __logf(tot);   // lse = m + log(sum exp(s-m))
    }

    // ---------------- pass 2: recompute + write ----------------
    float* outb = Out + (size_t)b * N_ * N_;
    for (int t = 0; t < NG / 4; ++t) {
        const int g = t * 4 + wave;
        const int c0 = g * 32;
        f32x16 acc = tile_mm(Bsb + (size_t)g * 2048, lane, a0, a1, a2, a3);
        #pragma unroll
        for (int r = 0; r < 16; ++r) {
            int row = rowbase + (r & 3) + 8 * (r >> 2) + 4 * half;
            float v = __expf(acc[r] - lse[r]);
            __builtin_nontemporal_store(v, &outb[(size_t)row * N_ + (c0 + mcol)]);
        }
    }
}

extern "C" void kernel_launch(void* const* d_in, const int* in_sizes, int n_in,
                              void* d_out, int out_size, void* d_ws, size_t ws_size,
                              hipStream_t stream) {
    const float* X = (const float*)d_in[0];
    float* Out     = (float*)d_out;

    bf16_t* Bs    = (bf16_t*)d_ws;                                   // 2 MB swizzled
    float*  norms = (float*)((char*)d_ws + (size_t)B_ * N_ * D_ * sizeof(bf16_t));

    swizzle_norm_kernel<<<B_ * NG, 256, 0, stream>>>(X, Bs, norms);
    softmax_xxt_kernel<<<B_ * NG, 256, 0, stream>>>(Bs, norms, Out);
}